// Round 6
// baseline (538.510 us; speedup 1.0000x reference)
//
#include <hip/hip_runtime.h>
#include <hip/hip_bf16.h>

typedef short short8 __attribute__((ext_vector_type(8)));
typedef float floatx4 __attribute__((ext_vector_type(4)));
using bf16 = __hip_bfloat16;

static constexpr int L = 2048, H = 2048, D = 4096, NS = 16, R = 128, KC = 4;
static constexpr int CCH = 64, TCH = L / CCH;        // 64 chunks x 32 steps
static constexpr int KSP = 16, KCHUNK = 4096 / KSP;  // split-K for ssm_p
static constexpr int ZOUT = 4, KOUT = 4096 / ZOUT;   // split-K for out GEMM

__device__ __forceinline__ void g2lds16(const void* g, void* l) {
  __builtin_amdgcn_global_load_lds((const __attribute__((address_space(1))) unsigned int*)g,
                                   (__attribute__((address_space(3))) unsigned int*)l,
                                   16, 0, 0);
}

// ---------------- elementwise fp32 -> bf16 cast ----------------
__global__ void cast_f2b(const float* __restrict__ in, bf16* __restrict__ out, int n) {
  int i = blockIdx.x * 256 + threadIdx.x;
  if (i < n) out[i] = __float2bfloat16(in[i]);
}

// ------------- weight transpose+cast (fp32 [Rr,Cc] -> bf16 [Cc,Rr]) -------------
__global__ void transpose_cast(const float* __restrict__ in, bf16* __restrict__ out,
                               int Rr, int Cc) {
  __shared__ float tile[32][33];
  int c0 = blockIdx.x * 32, r0 = blockIdx.y * 32;
  int tx = threadIdx.x, ty = threadIdx.y;  // 32 x 8
#pragma unroll
  for (int i = 0; i < 32; i += 8)
    tile[ty + i][tx] = in[(size_t)(r0 + ty + i) * Cc + (c0 + tx)];
  __syncthreads();
#pragma unroll
  for (int i = 0; i < 32; i += 8)
    out[(size_t)(c0 + ty + i) * Rr + (r0 + tx)] = __float2bfloat16(tile[tx][ty + i]);
}

// ------- dense bf16 MFMA GEMM (async staging): C[M,N] = A[M,K]*Bt[N,K]^T -------
// MODE 0: fp32 C.  MODE 1: bf16 C.  MODE 2: proj split (col<D -> bf16 Cb[L,D], else fp32 Cf[L,D]).
template <int MODE>
__global__ __launch_bounds__(256) void gemm_async(
    const bf16* __restrict__ A, int lda,
    const bf16* __restrict__ Bt, int ldb,
    float* __restrict__ Cf, bf16* __restrict__ Cb, int ldc, int K) {
  __shared__ short As[128 * 32];
  __shared__ short Bs[128 * 32];
  const int m0 = blockIdx.y * 128, n0 = blockIdx.x * 128;
  const int tid = threadIdx.x;
  const int lane = tid & 63;
  const int wave = tid >> 6;
  const int wm = (wave >> 1) * 64, wn = (wave & 1) * 64;
  const int lr = lane & 15, kq = lane >> 4;
  const int sr = lane >> 2, sc = (lane & 3) * 8;

  const bf16* Ab = A + (size_t)(m0 + wave * 16 + sr) * lda + sc;
  const bf16* Bb = Bt + (size_t)(n0 + wave * 16 + sr) * ldb + sc;
  short* Asw = &As[wave * 16 * 32];
  short* Bsw = &Bs[wave * 16 * 32];

  floatx4 acc[4][4];
#pragma unroll
  for (int i = 0; i < 4; i++)
#pragma unroll
    for (int j = 0; j < 4; j++)
#pragma unroll
      for (int r = 0; r < 4; r++) acc[i][j][r] = 0.f;

  for (int k0 = 0; k0 < K; k0 += 32) {
    __syncthreads();
#pragma unroll
    for (int j = 0; j < 2; j++) {
      g2lds16(Ab + (size_t)j * 64 * lda + k0, Asw + j * 64 * 32);
      g2lds16(Bb + (size_t)j * 64 * ldb + k0, Bsw + j * 64 * 32);
    }
    __syncthreads();
    short8 af[4], bfr[4];
#pragma unroll
    for (int i = 0; i < 4; i++)
      af[i] = *(const short8*)(&As[(wm + i * 16 + lr) * 32 + kq * 8]);
#pragma unroll
    for (int j = 0; j < 4; j++)
      bfr[j] = *(const short8*)(&Bs[(wn + j * 16 + lr) * 32 + kq * 8]);
#pragma unroll
    for (int i = 0; i < 4; i++)
#pragma unroll
      for (int j = 0; j < 4; j++)
        acc[i][j] = __builtin_amdgcn_mfma_f32_16x16x32_bf16(af[i], bfr[j], acc[i][j], 0, 0, 0);
  }

  const int rb = kq * 4;  // C/D: col = lane&15, row = (lane>>4)*4 + reg
#pragma unroll
  for (int i = 0; i < 4; i++)
#pragma unroll
    for (int j = 0; j < 4; j++) {
      int col = n0 + wn + j * 16 + lr;
      int row = m0 + wm + i * 16 + rb;
#pragma unroll
      for (int r = 0; r < 4; r++) {
        float v = acc[i][j][r];
        if (MODE == 0) {
          Cf[(size_t)(row + r) * ldc + col] = v;
        } else if (MODE == 1) {
          Cb[(size_t)(row + r) * ldc + col] = __float2bfloat16(v);
        } else {
          if (col < D) Cb[(size_t)(row + r) * D + col] = __float2bfloat16(v);
          else         Cf[(size_t)(row + r) * D + col - D] = v;
        }
      }
    }
}

// ------- split-K dense GEMM (async staging): P[z][M][N] partials -------
__global__ __launch_bounds__(256) void gemm_async_splitk(
    const bf16* __restrict__ A, int lda,
    const bf16* __restrict__ Bt, int ldb,
    float* __restrict__ P, int ldc, int kch) {
  __shared__ short As[128 * 32];
  __shared__ short Bs[128 * 32];
  const int m0 = blockIdx.y * 128, n0 = blockIdx.x * 128;
  const int kbeg = blockIdx.z * kch;
  float* C = P + (size_t)blockIdx.z * L * ldc;
  const int tid = threadIdx.x;
  const int lane = tid & 63;
  const int wave = tid >> 6;
  const int wm = (wave >> 1) * 64, wn = (wave & 1) * 64;
  const int lr = lane & 15, kq = lane >> 4;
  const int sr = lane >> 2, sc = (lane & 3) * 8;

  const bf16* Ab = A + (size_t)(m0 + wave * 16 + sr) * lda + sc;
  const bf16* Bb = Bt + (size_t)(n0 + wave * 16 + sr) * ldb + sc;
  short* Asw = &As[wave * 16 * 32];
  short* Bsw = &Bs[wave * 16 * 32];

  floatx4 acc[4][4];
#pragma unroll
  for (int i = 0; i < 4; i++)
#pragma unroll
    for (int j = 0; j < 4; j++)
#pragma unroll
      for (int r = 0; r < 4; r++) acc[i][j][r] = 0.f;

  for (int k0 = kbeg; k0 < kbeg + kch; k0 += 32) {
    __syncthreads();
#pragma unroll
    for (int j = 0; j < 2; j++) {
      g2lds16(Ab + (size_t)j * 64 * lda + k0, Asw + j * 64 * 32);
      g2lds16(Bb + (size_t)j * 64 * ldb + k0, Bsw + j * 64 * 32);
    }
    __syncthreads();
    short8 af[4], bfr[4];
#pragma unroll
    for (int i = 0; i < 4; i++)
      af[i] = *(const short8*)(&As[(wm + i * 16 + lr) * 32 + kq * 8]);
#pragma unroll
    for (int j = 0; j < 4; j++)
      bfr[j] = *(const short8*)(&Bs[(wn + j * 16 + lr) * 32 + kq * 8]);
#pragma unroll
    for (int i = 0; i < 4; i++)
#pragma unroll
      for (int j = 0; j < 4; j++)
        acc[i][j] = __builtin_amdgcn_mfma_f32_16x16x32_bf16(af[i], bfr[j], acc[i][j], 0, 0, 0);
  }

  const int rb = kq * 4;
#pragma unroll
  for (int i = 0; i < 4; i++)
#pragma unroll
    for (int j = 0; j < 4; j++) {
      int col = n0 + wn + j * 16 + lr;
      int row = m0 + wm + i * 16 + rb;
#pragma unroll
      for (int r = 0; r < 4; r++)
        C[(size_t)(row + r) * ldc + col] = acc[i][j][r];
    }
}

// ------- out split-K reduce (float4) -------
__global__ void out_reduce(const float* __restrict__ P, float* __restrict__ out) {
  int i = blockIdx.x * 256 + threadIdx.x;  // over L*H/4 float4s
  const int LH4 = L * H / 4;
  const floatx4* P4 = (const floatx4*)P;
  floatx4 s = P4[i];
#pragma unroll
  for (int z = 1; z < ZOUT; z++) s += P4[(size_t)z * LH4 + i];
  ((floatx4*)out)[i] = s;
}

// ------- split-K guarded GEMM for ssm_p: partial[z][M][N] over K-chunk -------
__global__ __launch_bounds__(256) void gemm_splitk(
    const bf16* __restrict__ A, int lda,
    const bf16* __restrict__ Bt, int ldb,
    float* __restrict__ P, int ldc, int N) {
  __shared__ short As[128 * 40];
  __shared__ short Bs[128 * 40];
  const int m0 = blockIdx.y * 128, n0 = blockIdx.x * 128;
  const int kbeg = blockIdx.z * KCHUNK;
  float* C = P + (size_t)blockIdx.z * L * ldc;
  const int tid = threadIdx.x;
  const int lane = tid & 63;
  const int wave = tid >> 6;
  const int wm = (wave >> 1) * 64, wn = (wave & 1) * 64;
  const int lr = lane & 15, kq = lane >> 4;
  const int srow = tid >> 2, scol = (tid & 3) * 8;

  floatx4 acc[4][4];
#pragma unroll
  for (int i = 0; i < 4; i++)
#pragma unroll
    for (int j = 0; j < 4; j++)
#pragma unroll
      for (int r = 0; r < 4; r++) acc[i][j][r] = 0.f;

  for (int k0 = kbeg; k0 < kbeg + KCHUNK; k0 += 32) {
    __syncthreads();
#pragma unroll
    for (int h = 0; h < 2; h++) {
      int r = srow + h * 64;
      short8 va = *(const short8*)((const short*)A + (size_t)(m0 + r) * lda + k0 + scol);
      *(short8*)(&As[r * 40 + scol]) = va;
    }
#pragma unroll
    for (int h = 0; h < 2; h++) {
      int r = srow + h * 64;
      short8 vb;
      if ((n0 + r) < N) {
        vb = *(const short8*)((const short*)Bt + (size_t)(n0 + r) * ldb + k0 + scol);
      } else {
#pragma unroll
        for (int q = 0; q < 8; q++) vb[q] = 0;
      }
      *(short8*)(&Bs[r * 40 + scol]) = vb;
    }
    __syncthreads();
    short8 af[4], bfr[4];
#pragma unroll
    for (int i = 0; i < 4; i++)
      af[i] = *(const short8*)(&As[(wm + i * 16 + lr) * 40 + kq * 8]);
#pragma unroll
    for (int j = 0; j < 4; j++)
      bfr[j] = *(const short8*)(&Bs[(wn + j * 16 + lr) * 40 + kq * 8]);
#pragma unroll
    for (int i = 0; i < 4; i++)
#pragma unroll
      for (int j = 0; j < 4; j++)
        acc[i][j] = __builtin_amdgcn_mfma_f32_16x16x32_bf16(af[i], bfr[j], acc[i][j], 0, 0, 0);
  }

  const int rb = kq * 4;
#pragma unroll
  for (int i = 0; i < 4; i++)
#pragma unroll
    for (int j = 0; j < 4; j++) {
      int col = n0 + wn + j * 16 + lr;
      if (col >= N) continue;
      int row = m0 + wm + i * 16 + rb;
#pragma unroll
      for (int r = 0; r < 4; r++)
        C[(size_t)(row + r) * ldc + col] = acc[i][j][r];
    }
}

// ------- split-K reduce + fused dt_in bf16 cast -------
__global__ void splitk_reduce(const float* __restrict__ P, float* __restrict__ ssmp,
                              bf16* __restrict__ dtin) {
  int idx = blockIdx.x * 256 + threadIdx.x;  // t*160 + c
  float s = 0.f;
#pragma unroll
  for (int z = 0; z < KSP; z++) s += P[(size_t)z * L * 160 + idx];
  ssmp[idx] = s;
  int t = idx / 160, c = idx - t * 160;
  if (c < R) dtin[t * R + c] = __float2bfloat16(s);
}

// ---------------- causal depthwise conv (K=4) + bias + SiLU ----------------
__global__ void conv_silu(const bf16* __restrict__ projh,
                          const float* __restrict__ conv_w, const float* __restrict__ conv_b,
                          bf16* __restrict__ hs_b) {
  int idx = blockIdx.x * 256 + threadIdx.x;  // t*D + d
  int d = idx & (D - 1), t = idx >> 12;
  float acc = conv_b[d];
#pragma unroll
  for (int k = 0; k < KC; k++) {
    int tt = t + k - (KC - 1);
    if (tt >= 0) acc += __bfloat162float(projh[(size_t)tt * D + d]) * conv_w[k * D + d];
  }
  float s = acc / (1.f + __expf(-acc));
  hs_b[idx] = __float2bfloat16(s);
}

__device__ __forceinline__ float softplusf(float v) {
  return (v > 20.f) ? v : log1pf(__expf(v));
}

// ---------------- scan phase 1: per-chunk local scan ----------------
__global__ __launch_bounds__(256) void scan_phase1(
    const bf16* __restrict__ dtraw, const float* __restrict__ b_dt,
    const bf16* __restrict__ hs_b, const float* __restrict__ ssmp,
    const float* __restrict__ A_log,
    float* __restrict__ sdt_out, float* __restrict__ S_out) {
  const int d = blockIdx.x * 256 + threadIdx.x;
  const int c = blockIdx.y;
  float An[NS];
#pragma unroll
  for (int n = 0; n < NS; n++) An[n] = -__expf(A_log[d * NS + n]);
  const float bdt = b_dt[d];
  float s[NS];
#pragma unroll
  for (int n = 0; n < NS; n++) s[n] = 0.f;
  float sdt = 0.f;
  const int t0 = c * TCH;
#pragma unroll 2
  for (int t = t0; t < t0 + TCH; t++) {
    float dtv = softplusf(__bfloat162float(dtraw[(size_t)t * D + d]) + bdt);
    float hsv = __bfloat162float(hs_b[(size_t)t * D + d]);
    sdt += dtv;
    float u = dtv * hsv;
    const float* Bp = ssmp + (size_t)t * 160 + 128;
#pragma unroll
    for (int n = 0; n < NS; n++) {
      float dA = __expf(An[n] * dtv);
      s[n] = dA * s[n] + Bp[n] * u;
    }
  }
  sdt_out[(size_t)c * D + d] = sdt;
  float* Sp = S_out + ((size_t)c * D + d) * NS;
#pragma unroll
  for (int n = 0; n < NS; n += 4)
    *(floatx4*)(Sp + n) = *(floatx4*)(s + n);
}

// ---------------- scan phase 2: sequential combine over chunks (pipelined) ----------------
__global__ __launch_bounds__(256) void scan_phase2(
    const float* __restrict__ sdt, const float* __restrict__ S,
    const float* __restrict__ A_log, float* __restrict__ I) {
  int g = blockIdx.x * 256 + threadIdx.x;  // d*16 + n
  int d = g >> 4;
  float An = -__expf(A_log[g]);
  float cur = 0.f;
  float sdt_n = sdt[d];
  float S_n = S[g];
  for (int c = 0; c < CCH; c++) {
    float sdt_c = sdt_n, S_c = S_n;
    if (c + 1 < CCH) {
      sdt_n = sdt[(size_t)(c + 1) * D + d];
      S_n = S[(size_t)(c + 1) * D * NS + g];
    }
    I[(size_t)c * D * NS + g] = cur;
    cur = __expf(An * sdt_c) * cur + S_c;
  }
}

// ---------------- scan phase 3: seeded per-chunk scan + fused epilogue ----------------
__global__ __launch_bounds__(256) void scan_phase3(
    const bf16* __restrict__ dtraw, const float* __restrict__ b_dt,
    const bf16* __restrict__ hs_b, const float* __restrict__ ssmp,
    const float* __restrict__ gate_f, const float* __restrict__ A_log,
    const float* __restrict__ D_param, const float* __restrict__ I,
    bf16* __restrict__ y_b) {
  const int d = blockIdx.x * 256 + threadIdx.x;
  const int c = blockIdx.y;
  float An[NS];
#pragma unroll
  for (int n = 0; n < NS; n++) An[n] = -__expf(A_log[d * NS + n]);
  const float bdt = b_dt[d];
  const float Dp = D_param[d];
  float s[NS];
  const float* Ip = I + ((size_t)c * D + d) * NS;
#pragma unroll
  for (int n = 0; n < NS; n += 4)
    *(floatx4*)(s + n) = *(const floatx4*)(Ip + n);
  const int t0 = c * TCH;
#pragma unroll 2
  for (int t = t0; t < t0 + TCH; t++) {
    float dtv = softplusf(__bfloat162float(dtraw[(size_t)t * D + d]) + bdt);
    float hsv = __bfloat162float(hs_b[(size_t)t * D + d]);
    float u = dtv * hsv;
    const float* Bp = ssmp + (size_t)t * 160 + 128;
    const float* Cp = ssmp + (size_t)t * 160 + 144;
    float y = 0.f;
#pragma unroll
    for (int n = 0; n < NS; n++) {
      float dA = __expf(An[n] * dtv);
      s[n] = dA * s[n] + Bp[n] * u;
      y += s[n] * Cp[n];
    }
    float gv = gate_f[(size_t)t * D + d];
    float yv = (y + hsv * Dp) * (gv / (1.f + __expf(-gv)));
    y_b[(size_t)t * D + d] = __float2bfloat16(yv);
  }
}

extern "C" void kernel_launch(void* const* d_in, const int* in_sizes, int n_in,
                              void* d_out, int out_size, void* d_ws, size_t ws_size,
                              hipStream_t stream) {
  const float* x      = (const float*)d_in[0];
  const float* W_in   = (const float*)d_in[1];
  const float* conv_w = (const float*)d_in[2];
  const float* conv_b = (const float*)d_in[3];
  const float* W_x    = (const float*)d_in[4];
  const float* W_dt   = (const float*)d_in[5];
  const float* b_dt   = (const float*)d_in[6];
  const float* A_log  = (const float*)d_in[7];
  const float* D_par  = (const float*)d_in[8];
  const float* W_out  = (const float*)d_in[9];
  float* outp = (float*)d_out;

  // ---- workspace layout with lifetime aliasing (peak ~210 MiB) ----
  char* ws = (char*)d_ws;
  size_t off = 0;
  auto alloc = [&](size_t bytes) {
    char* p = ws + off;
    off += (bytes + 255) & ~(size_t)255;
    return (void*)p;
  };
  // persistent region
  float* gate_f  = (float*)alloc((size_t)L * D * 4);            // 32 MiB (alive till phase3)
  bf16*  hs_b    = (bf16*) alloc((size_t)L * D * 2);            // 16 MiB
  float* ssmp    = (float*)alloc((size_t)L * 160 * 4);          // 1.25 MiB
  bf16*  dtin_b  = (bf16*) alloc((size_t)L * R * 2);            // 0.5 MiB
  bf16*  dtbuf_b = (bf16*) alloc((size_t)L * D * 2);            // 16 MiB
  bf16*  y_b     = (bf16*) alloc((size_t)L * D * 2);            // 16 MiB
  bf16*  WoutT   = (bf16*) alloc((size_t)H * D * 2);            // 16 MiB (read at the end)
  float* sdt     = (float*)alloc((size_t)CCH * D * 4);          // 1 MiB
  float* Sbuf    = (float*)alloc((size_t)CCH * D * NS * 4);     // 16 MiB
  float* Ibuf    = (float*)alloc((size_t)CCH * D * NS * 4);     // 16 MiB
  // transient region: layout A (early pipeline) aliased with layout B (part2)
  size_t tbase = off;
  bf16*  x_b     = (bf16*) alloc((size_t)L * H * 2);            // 8 MiB   dead after proj
  bf16*  WinT    = (bf16*) alloc((size_t)2 * D * H * 2);        // 32 MiB  dead after proj
  bf16*  WxT     = (bf16*) alloc((size_t)160 * D * 2);          // 1.25 MiB dead after ssm_p
  bf16*  WdtT   = (bf16*) alloc((size_t)D * R * 2);             // 1 MiB   dead after dt GEMM
  bf16*  projh_b = (bf16*) alloc((size_t)L * D * 2);            // 16 MiB  dead after conv
  float* part    = (float*)alloc((size_t)KSP * L * 160 * 4);    // 20 MiB  dead after reduce
  float* part2   = (float*)(ws + tbase);                        // 64 MiB, aliases layout A

  cast_f2b<<<(L * H) / 256, 256, 0, stream>>>(x, x_b, L * H);

  dim3 tb(32, 8);
  transpose_cast<<<dim3((2 * D) / 32, H / 32), tb, 0, stream>>>(W_in, WinT, H, 2 * D);
  transpose_cast<<<dim3(H / 32, D / 32), tb, 0, stream>>>(W_out, WoutT, D, H);
  transpose_cast<<<dim3(160 / 32, D / 32), tb, 0, stream>>>(W_x, WxT, D, 160);
  transpose_cast<<<dim3(D / 32, R / 32), tb, 0, stream>>>(W_dt, WdtT, R, D);

  // proj = x @ W_in  [L, 2D]; hs-half -> bf16 projh_b, gate-half -> fp32 gate_f
  gemm_async<2><<<dim3((2 * D) / 128, L / 128), 256, 0, stream>>>(
      x_b, H, WinT, H, gate_f, projh_b, D, H);
  // hs = silu(conv(projh)) -> bf16
  conv_silu<<<(L * D) / 256, 256, 0, stream>>>(projh_b, conv_w, conv_b, hs_b);
  // ssm_p = hs @ W_x  [L, 160] via split-K partials + reduce (fused dtin cast)
  gemm_splitk<<<dim3(2, L / 128, KSP), 256, 0, stream>>>(
      hs_b, D, WxT, D, part, 160, 160);
  splitk_reduce<<<(L * 160) / 256, 256, 0, stream>>>(part, ssmp, dtin_b);
  // dt_pre = dt_in @ W_dt  [L, D] bf16 (softplus folded into scan)
  gemm_async<1><<<dim3(D / 128, L / 128), 256, 0, stream>>>(
      dtin_b, R, WdtT, R, nullptr, dtbuf_b, D, R);

  // chunked scan
  scan_phase1<<<dim3(D / 256, CCH), 256, 0, stream>>>(
      dtbuf_b, b_dt, hs_b, ssmp, A_log, sdt, Sbuf);
  scan_phase2<<<(D * NS) / 256, 256, 0, stream>>>(sdt, Sbuf, A_log, Ibuf);
  scan_phase3<<<dim3(D / 256, CCH), 256, 0, stream>>>(
      dtbuf_b, b_dt, hs_b, ssmp, gate_f, A_log, D_par, Ibuf, y_b);

  // out = y @ W_out  [L, H] via split-K (Z=4, aliased transient region) + reduce
  gemm_async_splitk<<<dim3(H / 128, L / 128, ZOUT), 256, 0, stream>>>(
      y_b, D, WoutT, D, part2, H, KOUT);
  out_reduce<<<(L * H / 4) / 256, 256, 0, stream>>>(part2, outp);
}

// Round 7
// 529.415 us; speedup vs baseline: 1.0172x; 1.0172x over previous
//
#include <hip/hip_runtime.h>
#include <hip/hip_bf16.h>

typedef short short8 __attribute__((ext_vector_type(8)));
typedef float floatx4 __attribute__((ext_vector_type(4)));
using bf16 = __hip_bfloat16;

static constexpr int L = 2048, H = 2048, D = 4096, NS = 16, R = 128, KC = 4;
static constexpr int CCH = 64, TCH = L / CCH;        // 64 chunks x 32 steps
static constexpr int KSP = 16, KCHUNK = 4096 / KSP;  // split-K for ssm_p
static constexpr int ZOUT = 2, KOUT = 4096 / ZOUT;   // split-K for out GEMM (128x64 tiles)

__device__ __forceinline__ void g2lds16(const void* g, void* l) {
  __builtin_amdgcn_global_load_lds((const __attribute__((address_space(1))) unsigned int*)g,
                                   (__attribute__((address_space(3))) unsigned int*)l,
                                   16, 0, 0);
}

// ---------------- elementwise fp32 -> bf16 cast ----------------
__global__ void cast_f2b(const float* __restrict__ in, bf16* __restrict__ out, int n) {
  int i = blockIdx.x * 256 + threadIdx.x;
  if (i < n) out[i] = __float2bfloat16(in[i]);
}

// ------------- weight transpose+cast (fp32 [Rr,Cc] -> bf16 [Cc,Rr]) -------------
__global__ void transpose_cast(const float* __restrict__ in, bf16* __restrict__ out,
                               int Rr, int Cc) {
  __shared__ float tile[32][33];
  int c0 = blockIdx.x * 32, r0 = blockIdx.y * 32;
  int tx = threadIdx.x, ty = threadIdx.y;  // 32 x 8
#pragma unroll
  for (int i = 0; i < 32; i += 8)
    tile[ty + i][tx] = in[(size_t)(r0 + ty + i) * Cc + (c0 + tx)];
  __syncthreads();
#pragma unroll
  for (int i = 0; i < 32; i += 8)
    out[(size_t)(c0 + ty + i) * Rr + (r0 + tx)] = __float2bfloat16(tile[tx][ty + i]);
}

// ------- dense bf16 MFMA GEMM (async staging): C[M,N] = A[M,K]*Bt[N,K]^T -------
// MODE 1: bf16 C (ldc).  MODE 2: proj split — block col-half selects Cb (hs) or Cb2 (gate),
//         both bf16 [L,D]; selection is block-uniform (n0 multiples of 128, D=4096).
template <int MODE>
__global__ __launch_bounds__(256) void gemm_async(
    const bf16* __restrict__ A, int lda,
    const bf16* __restrict__ Bt, int ldb,
    bf16* __restrict__ Cb, bf16* __restrict__ Cb2, int ldc, int K) {
  __shared__ short As[128 * 32];
  __shared__ short Bs[128 * 32];
  const int m0 = blockIdx.y * 128, n0 = blockIdx.x * 128;
  const int tid = threadIdx.x;
  const int lane = tid & 63;
  const int wave = tid >> 6;
  const int wm = (wave >> 1) * 64, wn = (wave & 1) * 64;
  const int lr = lane & 15, kq = lane >> 4;
  const int sr = lane >> 2, sc = (lane & 3) * 8;

  const bf16* Ab = A + (size_t)(m0 + wave * 16 + sr) * lda + sc;
  const bf16* Bb = Bt + (size_t)(n0 + wave * 16 + sr) * ldb + sc;
  short* Asw = &As[wave * 16 * 32];
  short* Bsw = &Bs[wave * 16 * 32];

  floatx4 acc[4][4];
#pragma unroll
  for (int i = 0; i < 4; i++)
#pragma unroll
    for (int j = 0; j < 4; j++)
#pragma unroll
      for (int r = 0; r < 4; r++) acc[i][j][r] = 0.f;

  for (int k0 = 0; k0 < K; k0 += 32) {
    __syncthreads();
#pragma unroll
    for (int j = 0; j < 2; j++) {
      g2lds16(Ab + (size_t)j * 64 * lda + k0, Asw + j * 64 * 32);
      g2lds16(Bb + (size_t)j * 64 * ldb + k0, Bsw + j * 64 * 32);
    }
    __syncthreads();
    short8 af[4], bfr[4];
#pragma unroll
    for (int i = 0; i < 4; i++)
      af[i] = *(const short8*)(&As[(wm + i * 16 + lr) * 32 + kq * 8]);
#pragma unroll
    for (int j = 0; j < 4; j++)
      bfr[j] = *(const short8*)(&Bs[(wn + j * 16 + lr) * 32 + kq * 8]);
#pragma unroll
    for (int i = 0; i < 4; i++)
#pragma unroll
      for (int j = 0; j < 4; j++)
        acc[i][j] = __builtin_amdgcn_mfma_f32_16x16x32_bf16(af[i], bfr[j], acc[i][j], 0, 0, 0);
  }

  // block-uniform output selection for MODE 2
  bf16* base = Cb;
  int coff = 0, ld = ldc;
  if (MODE == 2) {
    if (n0 >= D) { base = Cb2; coff = D; }
    ld = D;
  }
  const int rb = kq * 4;  // C/D: col = lane&15, row = (lane>>4)*4 + reg
#pragma unroll
  for (int i = 0; i < 4; i++)
#pragma unroll
    for (int j = 0; j < 4; j++) {
      int col = n0 + wn + j * 16 + lr - coff;
      int row = m0 + wm + i * 16 + rb;
#pragma unroll
      for (int r = 0; r < 4; r++)
        base[(size_t)(row + r) * ld + col] = __float2bfloat16(acc[i][j][r]);
    }
}

// ------- out GEMM: split-K Z=2, tile 128(M) x 64(N), 4 blocks/CU -------
__global__ __launch_bounds__(256) void gemm_out(
    const bf16* __restrict__ A, int lda,
    const bf16* __restrict__ Bt, int ldb,
    float* __restrict__ P, int ldc) {
  __shared__ short As[128 * 32];
  __shared__ short Bs[64 * 32];
  const int m0 = blockIdx.y * 128, n0 = blockIdx.x * 64;
  const int kbeg = blockIdx.z * KOUT;
  float* C = P + (size_t)blockIdx.z * L * ldc;
  const int tid = threadIdx.x;
  const int lane = tid & 63;
  const int wave = tid >> 6;
  const int wm = (wave >> 1) * 64, wn = (wave & 1) * 32;
  const int lr = lane & 15, kq = lane >> 4;
  const int sr = lane >> 2, sc = (lane & 3) * 8;

  const bf16* Ab = A + (size_t)(m0 + wave * 16 + sr) * lda + sc;
  const bf16* Bb = Bt + (size_t)(n0 + wave * 16 + sr) * ldb + sc;
  short* Asw = &As[wave * 16 * 32];
  short* Bsw = &Bs[wave * 16 * 32];

  floatx4 acc[4][2];
#pragma unroll
  for (int i = 0; i < 4; i++)
#pragma unroll
    for (int j = 0; j < 2; j++)
#pragma unroll
      for (int r = 0; r < 4; r++) acc[i][j][r] = 0.f;

  for (int k0 = kbeg; k0 < kbeg + KOUT; k0 += 32) {
    __syncthreads();
    g2lds16(Ab + k0, Asw);
    g2lds16(Ab + (size_t)64 * lda + k0, Asw + 64 * 32);
    g2lds16(Bb + k0, Bsw);  // 4 waves x 16 rows = 64 rows of B
    __syncthreads();
    short8 af[4], bfr[2];
#pragma unroll
    for (int i = 0; i < 4; i++)
      af[i] = *(const short8*)(&As[(wm + i * 16 + lr) * 32 + kq * 8]);
#pragma unroll
    for (int j = 0; j < 2; j++)
      bfr[j] = *(const short8*)(&Bs[(wn + j * 16 + lr) * 32 + kq * 8]);
#pragma unroll
    for (int i = 0; i < 4; i++)
#pragma unroll
      for (int j = 0; j < 2; j++)
        acc[i][j] = __builtin_amdgcn_mfma_f32_16x16x32_bf16(af[i], bfr[j], acc[i][j], 0, 0, 0);
  }

  const int rb = kq * 4;
#pragma unroll
  for (int i = 0; i < 4; i++)
#pragma unroll
    for (int j = 0; j < 2; j++) {
      int col = n0 + wn + j * 16 + lr;
      int row = m0 + wm + i * 16 + rb;
#pragma unroll
      for (int r = 0; r < 4; r++)
        C[(size_t)(row + r) * ldc + col] = acc[i][j][r];
    }
}

// ------- out split-K reduce (float4) -------
__global__ void out_reduce(const float* __restrict__ P, float* __restrict__ out) {
  int i = blockIdx.x * 256 + threadIdx.x;  // over L*H/4 float4s
  const int LH4 = L * H / 4;
  const floatx4* P4 = (const floatx4*)P;
  floatx4 s = P4[i];
#pragma unroll
  for (int z = 1; z < ZOUT; z++) s += P4[(size_t)z * LH4 + i];
  ((floatx4*)out)[i] = s;
}

// ------- split-K guarded GEMM for ssm_p: partial[z][M][N] over K-chunk -------
__global__ __launch_bounds__(256) void gemm_splitk(
    const bf16* __restrict__ A, int lda,
    const bf16* __restrict__ Bt, int ldb,
    float* __restrict__ P, int ldc, int N) {
  __shared__ short As[128 * 40];
  __shared__ short Bs[128 * 40];
  const int m0 = blockIdx.y * 128, n0 = blockIdx.x * 128;
  const int kbeg = blockIdx.z * KCHUNK;
  float* C = P + (size_t)blockIdx.z * L * ldc;
  const int tid = threadIdx.x;
  const int lane = tid & 63;
  const int wave = tid >> 6;
  const int wm = (wave >> 1) * 64, wn = (wave & 1) * 64;
  const int lr = lane & 15, kq = lane >> 4;
  const int srow = tid >> 2, scol = (tid & 3) * 8;

  floatx4 acc[4][4];
#pragma unroll
  for (int i = 0; i < 4; i++)
#pragma unroll
    for (int j = 0; j < 4; j++)
#pragma unroll
      for (int r = 0; r < 4; r++) acc[i][j][r] = 0.f;

  for (int k0 = kbeg; k0 < kbeg + KCHUNK; k0 += 32) {
    __syncthreads();
#pragma unroll
    for (int h = 0; h < 2; h++) {
      int r = srow + h * 64;
      short8 va = *(const short8*)((const short*)A + (size_t)(m0 + r) * lda + k0 + scol);
      *(short8*)(&As[r * 40 + scol]) = va;
    }
#pragma unroll
    for (int h = 0; h < 2; h++) {
      int r = srow + h * 64;
      short8 vb;
      if ((n0 + r) < N) {
        vb = *(const short8*)((const short*)Bt + (size_t)(n0 + r) * ldb + k0 + scol);
      } else {
#pragma unroll
        for (int q = 0; q < 8; q++) vb[q] = 0;
      }
      *(short8*)(&Bs[r * 40 + scol]) = vb;
    }
    __syncthreads();
    short8 af[4], bfr[4];
#pragma unroll
    for (int i = 0; i < 4; i++)
      af[i] = *(const short8*)(&As[(wm + i * 16 + lr) * 40 + kq * 8]);
#pragma unroll
    for (int j = 0; j < 4; j++)
      bfr[j] = *(const short8*)(&Bs[(wn + j * 16 + lr) * 40 + kq * 8]);
#pragma unroll
    for (int i = 0; i < 4; i++)
#pragma unroll
      for (int j = 0; j < 4; j++)
        acc[i][j] = __builtin_amdgcn_mfma_f32_16x16x32_bf16(af[i], bfr[j], acc[i][j], 0, 0, 0);
  }

  const int rb = kq * 4;
#pragma unroll
  for (int i = 0; i < 4; i++)
#pragma unroll
    for (int j = 0; j < 4; j++) {
      int col = n0 + wn + j * 16 + lr;
      if (col >= N) continue;
      int row = m0 + wm + i * 16 + rb;
#pragma unroll
      for (int r = 0; r < 4; r++)
        C[(size_t)(row + r) * ldc + col] = acc[i][j][r];
    }
}

// ------- split-K reduce + fused dt_in bf16 cast -------
__global__ void splitk_reduce(const float* __restrict__ P, float* __restrict__ ssmp,
                              bf16* __restrict__ dtin) {
  int idx = blockIdx.x * 256 + threadIdx.x;  // t*160 + c
  float s = 0.f;
#pragma unroll
  for (int z = 0; z < KSP; z++) s += P[(size_t)z * L * 160 + idx];
  ssmp[idx] = s;
  int t = idx / 160, c = idx - t * 160;
  if (c < R) dtin[t * R + c] = __float2bfloat16(s);
}

// ---------------- causal depthwise conv (K=4) + bias + SiLU ----------------
__global__ void conv_silu(const bf16* __restrict__ projh,
                          const float* __restrict__ conv_w, const float* __restrict__ conv_b,
                          bf16* __restrict__ hs_b) {
  int idx = blockIdx.x * 256 + threadIdx.x;  // t*D + d
  int d = idx & (D - 1), t = idx >> 12;
  float acc = conv_b[d];
#pragma unroll
  for (int k = 0; k < KC; k++) {
    int tt = t + k - (KC - 1);
    if (tt >= 0) acc += __bfloat162float(projh[(size_t)tt * D + d]) * conv_w[k * D + d];
  }
  float s = acc / (1.f + __expf(-acc));
  hs_b[idx] = __float2bfloat16(s);
}

__device__ __forceinline__ float softplusf(float v) {
  return (v > 20.f) ? v : log1pf(__expf(v));
}

// ---------------- scan phase 1: per-chunk local scan ----------------
__global__ __launch_bounds__(256) void scan_phase1(
    const bf16* __restrict__ dtraw, const float* __restrict__ b_dt,
    const bf16* __restrict__ hs_b, const float* __restrict__ ssmp,
    const float* __restrict__ A_log,
    float* __restrict__ sdt_out, float* __restrict__ S_out) {
  const int d = blockIdx.x * 256 + threadIdx.x;
  const int c = blockIdx.y;
  float An[NS];
#pragma unroll
  for (int n = 0; n < NS; n++) An[n] = -__expf(A_log[d * NS + n]);
  const float bdt = b_dt[d];
  float s[NS];
#pragma unroll
  for (int n = 0; n < NS; n++) s[n] = 0.f;
  float sdt = 0.f;
  const int t0 = c * TCH;
#pragma unroll 2
  for (int t = t0; t < t0 + TCH; t++) {
    float dtv = softplusf(__bfloat162float(dtraw[(size_t)t * D + d]) + bdt);
    float hsv = __bfloat162float(hs_b[(size_t)t * D + d]);
    sdt += dtv;
    float u = dtv * hsv;
    const float* Bp = ssmp + (size_t)t * 160 + 128;
#pragma unroll
    for (int n = 0; n < NS; n++) {
      float dA = __expf(An[n] * dtv);
      s[n] = dA * s[n] + Bp[n] * u;
    }
  }
  sdt_out[(size_t)c * D + d] = sdt;
  float* Sp = S_out + ((size_t)c * D + d) * NS;
#pragma unroll
  for (int n = 0; n < NS; n += 4)
    *(floatx4*)(Sp + n) = *(floatx4*)(s + n);
}

// ---------------- scan phase 2: sequential combine over chunks (pipelined) ----------------
__global__ __launch_bounds__(256) void scan_phase2(
    const float* __restrict__ sdt, const float* __restrict__ S,
    const float* __restrict__ A_log, float* __restrict__ I) {
  int g = blockIdx.x * 256 + threadIdx.x;  // d*16 + n
  int d = g >> 4;
  float An = -__expf(A_log[g]);
  float cur = 0.f;
  float sdt_n = sdt[d];
  float S_n = S[g];
  for (int c = 0; c < CCH; c++) {
    float sdt_c = sdt_n, S_c = S_n;
    if (c + 1 < CCH) {
      sdt_n = sdt[(size_t)(c + 1) * D + d];
      S_n = S[(size_t)(c + 1) * D * NS + g];
    }
    I[(size_t)c * D * NS + g] = cur;
    cur = __expf(An * sdt_c) * cur + S_c;
  }
}

// ---------------- scan phase 3: seeded per-chunk scan + fused epilogue ----------------
__global__ __launch_bounds__(256) void scan_phase3(
    const bf16* __restrict__ dtraw, const float* __restrict__ b_dt,
    const bf16* __restrict__ hs_b, const float* __restrict__ ssmp,
    const bf16* __restrict__ gate_b, const float* __restrict__ A_log,
    const float* __restrict__ D_param, const float* __restrict__ I,
    bf16* __restrict__ y_b) {
  const int d = blockIdx.x * 256 + threadIdx.x;
  const int c = blockIdx.y;
  float An[NS];
#pragma unroll
  for (int n = 0; n < NS; n++) An[n] = -__expf(A_log[d * NS + n]);
  const float bdt = b_dt[d];
  const float Dp = D_param[d];
  float s[NS];
  const float* Ip = I + ((size_t)c * D + d) * NS;
#pragma unroll
  for (int n = 0; n < NS; n += 4)
    *(floatx4*)(s + n) = *(const floatx4*)(Ip + n);
  const int t0 = c * TCH;
#pragma unroll 2
  for (int t = t0; t < t0 + TCH; t++) {
    float dtv = softplusf(__bfloat162float(dtraw[(size_t)t * D + d]) + bdt);
    float hsv = __bfloat162float(hs_b[(size_t)t * D + d]);
    float u = dtv * hsv;
    const float* Bp = ssmp + (size_t)t * 160 + 128;
    const float* Cp = ssmp + (size_t)t * 160 + 144;
    float y = 0.f;
#pragma unroll
    for (int n = 0; n < NS; n++) {
      float dA = __expf(An[n] * dtv);
      s[n] = dA * s[n] + Bp[n] * u;
      y += s[n] * Cp[n];
    }
    float gv = __bfloat162float(gate_b[(size_t)t * D + d]);
    float yv = (y + hsv * Dp) * (gv / (1.f + __expf(-gv)));
    y_b[(size_t)t * D + d] = __float2bfloat16(yv);
  }
}

extern "C" void kernel_launch(void* const* d_in, const int* in_sizes, int n_in,
                              void* d_out, int out_size, void* d_ws, size_t ws_size,
                              hipStream_t stream) {
  const float* x      = (const float*)d_in[0];
  const float* W_in   = (const float*)d_in[1];
  const float* conv_w = (const float*)d_in[2];
  const float* conv_b = (const float*)d_in[3];
  const float* W_x    = (const float*)d_in[4];
  const float* W_dt   = (const float*)d_in[5];
  const float* b_dt   = (const float*)d_in[6];
  const float* A_log  = (const float*)d_in[7];
  const float* D_par  = (const float*)d_in[8];
  const float* W_out  = (const float*)d_in[9];
  float* outp = (float*)d_out;

  // ---- workspace layout with lifetime aliasing (peak ~192 MiB) ----
  char* ws = (char*)d_ws;
  size_t off = 0;
  auto alloc = [&](size_t bytes) {
    char* p = ws + off;
    off += (bytes + 255) & ~(size_t)255;
    return (void*)p;
  };
  // persistent region
  bf16*  gate_b  = (bf16*) alloc((size_t)L * D * 2);            // 16 MiB (alive till phase3)
  bf16*  hs_b    = (bf16*) alloc((size_t)L * D * 2);            // 16 MiB
  float* ssmp    = (float*)alloc((size_t)L * 160 * 4);          // 1.25 MiB
  bf16*  dtin_b  = (bf16*) alloc((size_t)L * R * 2);            // 0.5 MiB
  bf16*  dtbuf_b = (bf16*) alloc((size_t)L * D * 2);            // 16 MiB
  bf16*  y_b     = (bf16*) alloc((size_t)L * D * 2);            // 16 MiB
  bf16*  WoutT   = (bf16*) alloc((size_t)H * D * 2);            // 16 MiB (read at the end)
  float* sdt     = (float*)alloc((size_t)CCH * D * 4);          // 1 MiB
  float* Sbuf    = (float*)alloc((size_t)CCH * D * NS * 4);     // 16 MiB
  float* Ibuf    = (float*)alloc((size_t)CCH * D * NS * 4);     // 16 MiB
  // transient region: layout A (early pipeline) aliased with layout B (part2)
  size_t tbase = off;
  bf16*  x_b     = (bf16*) alloc((size_t)L * H * 2);            // 8 MiB   dead after proj
  bf16*  WinT    = (bf16*) alloc((size_t)2 * D * H * 2);        // 32 MiB  dead after proj
  bf16*  WxT     = (bf16*) alloc((size_t)160 * D * 2);          // 1.25 MiB dead after ssm_p
  bf16*  WdtT    = (bf16*) alloc((size_t)D * R * 2);            // 1 MiB   dead after dt GEMM
  bf16*  projh_b = (bf16*) alloc((size_t)L * D * 2);            // 16 MiB  dead after conv
  float* part    = (float*)alloc((size_t)KSP * L * 160 * 4);    // 20 MiB  dead after reduce
  float* part2   = (float*)(ws + tbase);                        // 32 MiB, aliases layout A

  cast_f2b<<<(L * H) / 256, 256, 0, stream>>>(x, x_b, L * H);

  dim3 tb(32, 8);
  transpose_cast<<<dim3((2 * D) / 32, H / 32), tb, 0, stream>>>(W_in, WinT, H, 2 * D);
  transpose_cast<<<dim3(H / 32, D / 32), tb, 0, stream>>>(W_out, WoutT, D, H);
  transpose_cast<<<dim3(160 / 32, D / 32), tb, 0, stream>>>(W_x, WxT, D, 160);
  transpose_cast<<<dim3(D / 32, R / 32), tb, 0, stream>>>(W_dt, WdtT, R, D);

  // proj = x @ W_in  [L, 2D]; hs-half -> bf16 projh_b, gate-half -> bf16 gate_b
  gemm_async<2><<<dim3((2 * D) / 128, L / 128), 256, 0, stream>>>(
      x_b, H, WinT, H, projh_b, gate_b, D, H);
  // hs = silu(conv(projh)) -> bf16
  conv_silu<<<(L * D) / 256, 256, 0, stream>>>(projh_b, conv_w, conv_b, hs_b);
  // ssm_p = hs @ W_x  [L, 160] via split-K partials + reduce (fused dtin cast)
  gemm_splitk<<<dim3(2, L / 128, KSP), 256, 0, stream>>>(
      hs_b, D, WxT, D, part, 160, 160);
  splitk_reduce<<<(L * 160) / 256, 256, 0, stream>>>(part, ssmp, dtin_b);
  // dt_pre = dt_in @ W_dt  [L, D] bf16 (softplus folded into scan)
  gemm_async<1><<<dim3(D / 128, L / 128), 256, 0, stream>>>(
      dtin_b, R, WdtT, R, dtbuf_b, nullptr, D, R);

  // chunked scan
  scan_phase1<<<dim3(D / 256, CCH), 256, 0, stream>>>(
      dtbuf_b, b_dt, hs_b, ssmp, A_log, sdt, Sbuf);
  scan_phase2<<<(D * NS) / 256, 256, 0, stream>>>(sdt, Sbuf, A_log, Ibuf);
  scan_phase3<<<dim3(D / 256, CCH), 256, 0, stream>>>(
      dtbuf_b, b_dt, hs_b, ssmp, gate_b, A_log, D_par, Ibuf, y_b);

  // out = y @ W_out  [L, H] via split-K Z=2, 128x64 tiles (1024 blocks = 4/CU) + reduce
  gemm_out<<<dim3(H / 64, L / 128, ZOUT), 256, 0, stream>>>(
      y_b, D, WoutT, D, part2, H);
  out_reduce<<<(L * H / 4) / 256, 256, 0, stream>>>(part2, outp);
}

// Round 8
// 506.430 us; speedup vs baseline: 1.0633x; 1.0454x over previous
//
#include <hip/hip_runtime.h>
#include <hip/hip_bf16.h>

typedef short short8 __attribute__((ext_vector_type(8)));
typedef float floatx4 __attribute__((ext_vector_type(4)));
using bf16 = __hip_bfloat16;

static constexpr int L = 2048, H = 2048, D = 4096, NS = 16, R = 128, KC = 4;
static constexpr int CCH = 64, TCH = L / CCH;        // 64 chunks x 32 steps
static constexpr int KSP = 16, KCHUNK = 4096 / KSP;  // split-K for ssm_p
static constexpr int ZOUT = 4, KOUT = 4096 / ZOUT;   // split-K for out GEMM

__device__ __forceinline__ void g2lds16(const void* g, void* l) {
  __builtin_amdgcn_global_load_lds((const __attribute__((address_space(1))) unsigned int*)g,
                                   (__attribute__((address_space(3))) unsigned int*)l,
                                   16, 0, 0);
}

// ---------------- elementwise fp32 -> bf16 cast ----------------
__global__ void cast_f2b(const float* __restrict__ in, bf16* __restrict__ out, int n) {
  int i = blockIdx.x * 256 + threadIdx.x;
  if (i < n) out[i] = __float2bfloat16(in[i]);
}

// ------------- weight transpose+cast (fp32 [Rr,Cc] -> bf16 [Cc,Rr]) -------------
__global__ void transpose_cast(const float* __restrict__ in, bf16* __restrict__ out,
                               int Rr, int Cc) {
  __shared__ float tile[32][33];
  int c0 = blockIdx.x * 32, r0 = blockIdx.y * 32;
  int tx = threadIdx.x, ty = threadIdx.y;  // 32 x 8
#pragma unroll
  for (int i = 0; i < 32; i += 8)
    tile[ty + i][tx] = in[(size_t)(r0 + ty + i) * Cc + (c0 + tx)];
  __syncthreads();
#pragma unroll
  for (int i = 0; i < 32; i += 8)
    out[(size_t)(c0 + ty + i) * Rr + (r0 + tx)] = __float2bfloat16(tile[tx][ty + i]);
}

// ------- dense bf16 MFMA GEMM (async staging, BK=64 as 2x BK32 stages) -------
// C[M,N] = A[M,K]*Bt[N,K]^T
// MODE 1: bf16 C (ldc).
// MODE 2: proj split — block col-half selects Cb (hs) or Cb2 (gate), both bf16 [L,D].
// MODE 3: split-K bf16 partials: kbeg = blockIdx.z*K, C = Cb + blockIdx.z*L*ldc.
// K must be a multiple of 64.
template <int MODE>
__global__ __launch_bounds__(256) void gemm_async(
    const bf16* __restrict__ A, int lda,
    const bf16* __restrict__ Bt, int ldb,
    bf16* __restrict__ Cb, bf16* __restrict__ Cb2, int ldc, int K) {
  __shared__ short As[2 * 128 * 32];
  __shared__ short Bs[2 * 128 * 32];
  const int m0 = blockIdx.y * 128, n0 = blockIdx.x * 128;
  const int kbeg = (MODE == 3) ? blockIdx.z * K : 0;
  const int tid = threadIdx.x;
  const int lane = tid & 63;
  const int wave = tid >> 6;
  const int wm = (wave >> 1) * 64, wn = (wave & 1) * 64;
  const int lr = lane & 15, kq = lane >> 4;
  const int sr = lane >> 2, sc = (lane & 3) * 8;

  const bf16* Ab = A + (size_t)(m0 + wave * 16 + sr) * lda + sc;
  const bf16* Bb = Bt + (size_t)(n0 + wave * 16 + sr) * ldb + sc;
  short* Asw = &As[wave * 16 * 32];
  short* Bsw = &Bs[wave * 16 * 32];

  floatx4 acc[4][4];
#pragma unroll
  for (int i = 0; i < 4; i++)
#pragma unroll
    for (int j = 0; j < 4; j++)
#pragma unroll
      for (int r = 0; r < 4; r++) acc[i][j][r] = 0.f;

  for (int k0 = kbeg; k0 < kbeg + K; k0 += 64) {
    __syncthreads();
#pragma unroll
    for (int h = 0; h < 2; h++) {
      int kk = k0 + h * 32;
#pragma unroll
      for (int j = 0; j < 2; j++) {
        g2lds16(Ab + (size_t)j * 64 * lda + kk, Asw + h * 4096 + j * 64 * 32);
        g2lds16(Bb + (size_t)j * 64 * ldb + kk, Bsw + h * 4096 + j * 64 * 32);
      }
    }
    __syncthreads();
#pragma unroll
    for (int h = 0; h < 2; h++) {
      short8 af[4], bfr[4];
#pragma unroll
      for (int i = 0; i < 4; i++)
        af[i] = *(const short8*)(&As[h * 4096 + (wm + i * 16 + lr) * 32 + kq * 8]);
#pragma unroll
      for (int j = 0; j < 4; j++)
        bfr[j] = *(const short8*)(&Bs[h * 4096 + (wn + j * 16 + lr) * 32 + kq * 8]);
#pragma unroll
      for (int i = 0; i < 4; i++)
#pragma unroll
        for (int j = 0; j < 4; j++)
          acc[i][j] = __builtin_amdgcn_mfma_f32_16x16x32_bf16(af[i], bfr[j], acc[i][j], 0, 0, 0);
    }
  }

  // block-uniform output selection
  bf16* base = Cb;
  int coff = 0, ld = ldc;
  if (MODE == 2) {
    if (n0 >= D) { base = Cb2; coff = D; }
    ld = D;
  }
  if (MODE == 3) base = Cb + (size_t)blockIdx.z * L * ldc;
  const int rb = kq * 4;  // C/D: col = lane&15, row = (lane>>4)*4 + reg
#pragma unroll
  for (int i = 0; i < 4; i++)
#pragma unroll
    for (int j = 0; j < 4; j++) {
      int col = n0 + wn + j * 16 + lr - coff;
      int row = m0 + wm + i * 16 + rb;
#pragma unroll
      for (int r = 0; r < 4; r++)
        base[(size_t)(row + r) * ld + col] = __float2bfloat16(acc[i][j][r]);
    }
}

// ------- out split-K reduce: bf16 partials -> fp32, 8 elems/thread -------
__global__ void out_reduce(const unsigned short* __restrict__ P, float* __restrict__ out) {
  int i = blockIdx.x * 256 + threadIdx.x;
  const size_t LH = (size_t)L * H;
  float acc[8];
#pragma unroll
  for (int e = 0; e < 8; e++) acc[e] = 0.f;
#pragma unroll
  for (int z = 0; z < ZOUT; z++) {
    short8 v = *(const short8*)(P + z * LH + (size_t)i * 8);
#pragma unroll
    for (int e = 0; e < 8; e++)
      acc[e] += __uint_as_float(((unsigned)(unsigned short)v[e]) << 16);
  }
#pragma unroll
  for (int q = 0; q < 2; q++) {
    floatx4 o;
#pragma unroll
    for (int r = 0; r < 4; r++) o[r] = acc[q * 4 + r];
    *(floatx4*)(out + (size_t)i * 8 + q * 4) = o;
  }
}

// ------- split-K guarded GEMM for ssm_p: partial[z][M][N] over K-chunk -------
__global__ __launch_bounds__(256) void gemm_splitk(
    const bf16* __restrict__ A, int lda,
    const bf16* __restrict__ Bt, int ldb,
    float* __restrict__ P, int ldc, int N) {
  __shared__ short As[128 * 40];
  __shared__ short Bs[128 * 40];
  const int m0 = blockIdx.y * 128, n0 = blockIdx.x * 128;
  const int kbeg = blockIdx.z * KCHUNK;
  float* C = P + (size_t)blockIdx.z * L * ldc;
  const int tid = threadIdx.x;
  const int lane = tid & 63;
  const int wave = tid >> 6;
  const int wm = (wave >> 1) * 64, wn = (wave & 1) * 64;
  const int lr = lane & 15, kq = lane >> 4;
  const int srow = tid >> 2, scol = (tid & 3) * 8;

  floatx4 acc[4][4];
#pragma unroll
  for (int i = 0; i < 4; i++)
#pragma unroll
    for (int j = 0; j < 4; j++)
#pragma unroll
      for (int r = 0; r < 4; r++) acc[i][j][r] = 0.f;

  for (int k0 = kbeg; k0 < kbeg + KCHUNK; k0 += 32) {
    __syncthreads();
#pragma unroll
    for (int h = 0; h < 2; h++) {
      int r = srow + h * 64;
      short8 va = *(const short8*)((const short*)A + (size_t)(m0 + r) * lda + k0 + scol);
      *(short8*)(&As[r * 40 + scol]) = va;
    }
#pragma unroll
    for (int h = 0; h < 2; h++) {
      int r = srow + h * 64;
      short8 vb;
      if ((n0 + r) < N) {
        vb = *(const short8*)((const short*)Bt + (size_t)(n0 + r) * ldb + k0 + scol);
      } else {
#pragma unroll
        for (int q = 0; q < 8; q++) vb[q] = 0;
      }
      *(short8*)(&Bs[r * 40 + scol]) = vb;
    }
    __syncthreads();
    short8 af[4], bfr[4];
#pragma unroll
    for (int i = 0; i < 4; i++)
      af[i] = *(const short8*)(&As[(wm + i * 16 + lr) * 40 + kq * 8]);
#pragma unroll
    for (int j = 0; j < 4; j++)
      bfr[j] = *(const short8*)(&Bs[(wn + j * 16 + lr) * 40 + kq * 8]);
#pragma unroll
    for (int i = 0; i < 4; i++)
#pragma unroll
      for (int j = 0; j < 4; j++)
        acc[i][j] = __builtin_amdgcn_mfma_f32_16x16x32_bf16(af[i], bfr[j], acc[i][j], 0, 0, 0);
  }

  const int rb = kq * 4;
#pragma unroll
  for (int i = 0; i < 4; i++)
#pragma unroll
    for (int j = 0; j < 4; j++) {
      int col = n0 + wn + j * 16 + lr;
      if (col >= N) continue;
      int row = m0 + wm + i * 16 + rb;
#pragma unroll
      for (int r = 0; r < 4; r++)
        C[(size_t)(row + r) * ldc + col] = acc[i][j][r];
    }
}

// ------- split-K reduce + fused dt_in bf16 cast -------
__global__ void splitk_reduce(const float* __restrict__ P, float* __restrict__ ssmp,
                              bf16* __restrict__ dtin) {
  int idx = blockIdx.x * 256 + threadIdx.x;  // t*160 + c
  float s = 0.f;
#pragma unroll
  for (int z = 0; z < KSP; z++) s += P[(size_t)z * L * 160 + idx];
  ssmp[idx] = s;
  int t = idx / 160, c = idx - t * 160;
  if (c < R) dtin[t * R + c] = __float2bfloat16(s);
}

// ---------------- causal depthwise conv (K=4) + bias + SiLU ----------------
__global__ void conv_silu(const bf16* __restrict__ projh,
                          const float* __restrict__ conv_w, const float* __restrict__ conv_b,
                          bf16* __restrict__ hs_b) {
  int idx = blockIdx.x * 256 + threadIdx.x;  // t*D + d
  int d = idx & (D - 1), t = idx >> 12;
  float acc = conv_b[d];
#pragma unroll
  for (int k = 0; k < KC; k++) {
    int tt = t + k - (KC - 1);
    if (tt >= 0) acc += __bfloat162float(projh[(size_t)tt * D + d]) * conv_w[k * D + d];
  }
  float s = acc / (1.f + __expf(-acc));
  hs_b[idx] = __float2bfloat16(s);
}

__device__ __forceinline__ float softplusf(float v) {
  return (v > 20.f) ? v : log1pf(__expf(v));
}

// ---------------- scan phase 1: per-chunk local scan ----------------
__global__ __launch_bounds__(256) void scan_phase1(
    const bf16* __restrict__ dtraw, const float* __restrict__ b_dt,
    const bf16* __restrict__ hs_b, const float* __restrict__ ssmp,
    const float* __restrict__ A_log,
    float* __restrict__ sdt_out, float* __restrict__ S_out) {
  const int d = blockIdx.x * 256 + threadIdx.x;
  const int c = blockIdx.y;
  float An[NS];
#pragma unroll
  for (int n = 0; n < NS; n++) An[n] = -__expf(A_log[d * NS + n]);
  const float bdt = b_dt[d];
  float s[NS];
#pragma unroll
  for (int n = 0; n < NS; n++) s[n] = 0.f;
  float sdt = 0.f;
  const int t0 = c * TCH;
#pragma unroll 2
  for (int t = t0; t < t0 + TCH; t++) {
    float dtv = softplusf(__bfloat162float(dtraw[(size_t)t * D + d]) + bdt);
    float hsv = __bfloat162float(hs_b[(size_t)t * D + d]);
    sdt += dtv;
    float u = dtv * hsv;
    const float* Bp = ssmp + (size_t)t * 160 + 128;
#pragma unroll
    for (int n = 0; n < NS; n++) {
      float dA = __expf(An[n] * dtv);
      s[n] = dA * s[n] + Bp[n] * u;
    }
  }
  sdt_out[(size_t)c * D + d] = sdt;
  float* Sp = S_out + ((size_t)c * D + d) * NS;
#pragma unroll
  for (int n = 0; n < NS; n += 4)
    *(floatx4*)(Sp + n) = *(floatx4*)(s + n);
}

// ---------------- scan phase 2: sequential combine over chunks (pipelined) ----------------
__global__ __launch_bounds__(256) void scan_phase2(
    const float* __restrict__ sdt, const float* __restrict__ S,
    const float* __restrict__ A_log, float* __restrict__ I) {
  int g = blockIdx.x * 256 + threadIdx.x;  // d*16 + n
  int d = g >> 4;
  float An = -__expf(A_log[g]);
  float cur = 0.f;
  float sdt_n = sdt[d];
  float S_n = S[g];
  for (int c = 0; c < CCH; c++) {
    float sdt_c = sdt_n, S_c = S_n;
    if (c + 1 < CCH) {
      sdt_n = sdt[(size_t)(c + 1) * D + d];
      S_n = S[(size_t)(c + 1) * D * NS + g];
    }
    I[(size_t)c * D * NS + g] = cur;
    cur = __expf(An * sdt_c) * cur + S_c;
  }
}

// ---------------- scan phase 3: seeded per-chunk scan + fused epilogue ----------------
__global__ __launch_bounds__(256) void scan_phase3(
    const bf16* __restrict__ dtraw, const float* __restrict__ b_dt,
    const bf16* __restrict__ hs_b, const float* __restrict__ ssmp,
    const bf16* __restrict__ gate_b, const float* __restrict__ A_log,
    const float* __restrict__ D_param, const float* __restrict__ I,
    bf16* __restrict__ y_b) {
  const int d = blockIdx.x * 256 + threadIdx.x;
  const int c = blockIdx.y;
  float An[NS];
#pragma unroll
  for (int n = 0; n < NS; n++) An[n] = -__expf(A_log[d * NS + n]);
  const float bdt = b_dt[d];
  const float Dp = D_param[d];
  float s[NS];
  const float* Ip = I + ((size_t)c * D + d) * NS;
#pragma unroll
  for (int n = 0; n < NS; n += 4)
    *(floatx4*)(s + n) = *(const floatx4*)(Ip + n);
  const int t0 = c * TCH;
#pragma unroll 2
  for (int t = t0; t < t0 + TCH; t++) {
    float dtv = softplusf(__bfloat162float(dtraw[(size_t)t * D + d]) + bdt);
    float hsv = __bfloat162float(hs_b[(size_t)t * D + d]);
    float u = dtv * hsv;
    const float* Bp = ssmp + (size_t)t * 160 + 128;
    const float* Cp = ssmp + (size_t)t * 160 + 144;
    float y = 0.f;
#pragma unroll
    for (int n = 0; n < NS; n++) {
      float dA = __expf(An[n] * dtv);
      s[n] = dA * s[n] + Bp[n] * u;
      y += s[n] * Cp[n];
    }
    float gv = __bfloat162float(gate_b[(size_t)t * D + d]);
    float yv = (y + hsv * Dp) * (gv / (1.f + __expf(-gv)));
    y_b[(size_t)t * D + d] = __float2bfloat16(yv);
  }
}

extern "C" void kernel_launch(void* const* d_in, const int* in_sizes, int n_in,
                              void* d_out, int out_size, void* d_ws, size_t ws_size,
                              hipStream_t stream) {
  const float* x      = (const float*)d_in[0];
  const float* W_in   = (const float*)d_in[1];
  const float* conv_w = (const float*)d_in[2];
  const float* conv_b = (const float*)d_in[3];
  const float* W_x    = (const float*)d_in[4];
  const float* W_dt   = (const float*)d_in[5];
  const float* b_dt   = (const float*)d_in[6];
  const float* A_log  = (const float*)d_in[7];
  const float* D_par  = (const float*)d_in[8];
  const float* W_out  = (const float*)d_in[9];
  float* outp = (float*)d_out;

  // ---- workspace layout with lifetime aliasing (peak ~192 MiB) ----
  char* ws = (char*)d_ws;
  size_t off = 0;
  auto alloc = [&](size_t bytes) {
    char* p = ws + off;
    off += (bytes + 255) & ~(size_t)255;
    return (void*)p;
  };
  // persistent region
  bf16*  gate_b  = (bf16*) alloc((size_t)L * D * 2);            // 16 MiB (alive till phase3)
  bf16*  hs_b    = (bf16*) alloc((size_t)L * D * 2);            // 16 MiB
  float* ssmp    = (float*)alloc((size_t)L * 160 * 4);          // 1.25 MiB
  bf16*  dtin_b  = (bf16*) alloc((size_t)L * R * 2);            // 0.5 MiB
  bf16*  dtbuf_b = (bf16*) alloc((size_t)L * D * 2);            // 16 MiB
  bf16*  y_b     = (bf16*) alloc((size_t)L * D * 2);            // 16 MiB
  bf16*  WoutT   = (bf16*) alloc((size_t)H * D * 2);            // 16 MiB (read at the end)
  float* sdt     = (float*)alloc((size_t)CCH * D * 4);          // 1 MiB
  float* Sbuf    = (float*)alloc((size_t)CCH * D * NS * 4);     // 16 MiB
  float* Ibuf    = (float*)alloc((size_t)CCH * D * NS * 4);     // 16 MiB
  // transient region: layout A (early pipeline) aliased with layout B (part2)
  size_t tbase = off;
  bf16*  x_b     = (bf16*) alloc((size_t)L * H * 2);            // 8 MiB   dead after proj
  bf16*  WinT    = (bf16*) alloc((size_t)2 * D * H * 2);        // 32 MiB  dead after proj
  bf16*  WxT     = (bf16*) alloc((size_t)160 * D * 2);          // 1.25 MiB dead after ssm_p
  bf16*  WdtT    = (bf16*) alloc((size_t)D * R * 2);            // 1 MiB   dead after dt GEMM
  bf16*  projh_b = (bf16*) alloc((size_t)L * D * 2);            // 16 MiB  dead after conv
  float* part    = (float*)alloc((size_t)KSP * L * 160 * 4);    // 20 MiB  dead after reduce
  bf16*  part2   = (bf16*)(ws + tbase);                         // 32 MiB (Z=4 bf16), aliases A

  cast_f2b<<<(L * H) / 256, 256, 0, stream>>>(x, x_b, L * H);

  dim3 tb(32, 8);
  transpose_cast<<<dim3((2 * D) / 32, H / 32), tb, 0, stream>>>(W_in, WinT, H, 2 * D);
  transpose_cast<<<dim3(H / 32, D / 32), tb, 0, stream>>>(W_out, WoutT, D, H);
  transpose_cast<<<dim3(160 / 32, D / 32), tb, 0, stream>>>(W_x, WxT, D, 160);
  transpose_cast<<<dim3(D / 32, R / 32), tb, 0, stream>>>(W_dt, WdtT, R, D);

  // proj = x @ W_in  [L, 2D]; hs-half -> bf16 projh_b, gate-half -> bf16 gate_b
  gemm_async<2><<<dim3((2 * D) / 128, L / 128), 256, 0, stream>>>(
      x_b, H, WinT, H, projh_b, gate_b, D, H);
  // hs = silu(conv(projh)) -> bf16
  conv_silu<<<(L * D) / 256, 256, 0, stream>>>(projh_b, conv_w, conv_b, hs_b);
  // ssm_p = hs @ W_x  [L, 160] via split-K partials + reduce (fused dtin cast)
  gemm_splitk<<<dim3(2, L / 128, KSP), 256, 0, stream>>>(
      hs_b, D, WxT, D, part, 160, 160);
  splitk_reduce<<<(L * 160) / 256, 256, 0, stream>>>(part, ssmp, dtin_b);
  // dt_pre = dt_in @ W_dt  [L, D] bf16 (softplus folded into scan)
  gemm_async<1><<<dim3(D / 128, L / 128), 256, 0, stream>>>(
      dtin_b, R, WdtT, R, dtbuf_b, nullptr, D, R);

  // chunked scan
  scan_phase1<<<dim3(D / 256, CCH), 256, 0, stream>>>(
      dtbuf_b, b_dt, hs_b, ssmp, A_log, sdt, Sbuf);
  scan_phase2<<<(D * NS) / 256, 256, 0, stream>>>(sdt, Sbuf, A_log, Ibuf);
  scan_phase3<<<dim3(D / 256, CCH), 256, 0, stream>>>(
      dtbuf_b, b_dt, hs_b, ssmp, gate_b, A_log, D_par, Ibuf, y_b);

  // out = y @ W_out  [L, H]: Z=4 split-K, 128x128 tiles, bf16 partials + reduce
  gemm_async<3><<<dim3(H / 128, L / 128, ZOUT), 256, 0, stream>>>(
      y_b, D, WoutT, D, part2, nullptr, H, KOUT);
  out_reduce<<<(L * H) / (256 * 8), 256, 0, stream>>>((const unsigned short*)part2, outp);
}